// Round 14
// baseline (33.830 us; speedup 1.0000x reference)
//
#include <hip/hip_runtime.h>

#define B_   1024
#define DIM_ 512
#define L_   512
#define NOUT 1536
#define G_   16    // interpolation grid points per batch
#define LDA  40    // LDS row stride in ushorts (80 B): 2-way-max bank aliasing

typedef __attribute__((ext_vector_type(8))) short short8;
typedef __attribute__((ext_vector_type(4))) float f32x4;

// packed fp32x2 -> bf16x2 (RNE), one VALU op
__device__ __forceinline__ unsigned int cvtpk(float lo, float hi) {
  unsigned int r;
  asm("v_cvt_pk_bf16_f32 %0, %1, %2" : "=v"(r) : "v"(lo), "v"(hi));
  return r;
}

struct Chunk { float4 al, ah, bl, bh; };

// ---------------- Kernel A: fused cvt + MFMA GEMM + in_proj ----------------
// Exact R11 winner: 64x64 tile, BK=32, 4 waves x 32x32 quadrant, 2-deep
// register prefetch, fp32->bf16 cvt during staging, XCD-aware swizzle
// (3 col-tiles/XCD -> x + w panel L2-resident). No launch_bounds VGPR cap
// (R13 lesson: capping with big prefetch state spills).
__global__ __launch_bounds__(256) void gemm_kernel(
    const float* __restrict__ x, const float* __restrict__ w,
    const float* __restrict__ ipw, const float* __restrict__ ipb,
    float* __restrict__ qp, float* __restrict__ kvp)
{
  __shared__ unsigned short aT[2][64 * LDA];   // 10 KB
  __shared__ unsigned short bT[2][64 * LDA];   // 10 KB

  const int tid  = threadIdx.x;
  const int lane = tid & 63;
  const int wv   = tid >> 6;
  const int bid  = blockIdx.x;
  const int xcd  = bid & 7, slot = bid >> 3;   // HW: xcd = dispatch_id % 8
  const int cb   = xcd * 3 + (slot >> 4);      // 3 col-tiles per XCD
  const int rb   = slot & 15;
  const int row0 = rb * 64;
  const int col0 = cb * 64;

  const int sr = tid >> 2;
  const int sc = (tid & 3) * 8;
  const float* xg = &x[(size_t)(row0 + sr) * DIM_ + sc];
  const float* wg = &w[(size_t)(col0 + sr) * DIM_ + sc];
  const int soff = sr * LDA + sc;

  const int wr = wv >> 1, wc = wv & 1;
  const int lm = lane & 15;
  const int kq = (lane >> 4) * 8;
  const int aoff0 = (wr * 32 + lm) * LDA + kq;
  const int boff0 = (wc * 32 + lm) * LDA + kq;

  f32x4 acc00 = {0,0,0,0}, acc01 = {0,0,0,0}, acc10 = {0,0,0,0}, acc11 = {0,0,0,0};

#define LOADC(dst, k0) do { \
    (dst).al = *(const float4*)(xg + (k0));     \
    (dst).ah = *(const float4*)(xg + (k0) + 4); \
    (dst).bl = *(const float4*)(wg + (k0));     \
    (dst).bh = *(const float4*)(wg + (k0) + 4); } while (0)
#define STORE_LDS(src, buf) do { \
    uint4 av_ = { cvtpk((src).al.x,(src).al.y), cvtpk((src).al.z,(src).al.w), \
                  cvtpk((src).ah.x,(src).ah.y), cvtpk((src).ah.z,(src).ah.w) }; \
    uint4 bv_ = { cvtpk((src).bl.x,(src).bl.y), cvtpk((src).bl.z,(src).bl.w), \
                  cvtpk((src).bh.x,(src).bh.y), cvtpk((src).bh.z,(src).bh.w) }; \
    *(uint4*)&aT[buf][soff] = av_; \
    *(uint4*)&bT[buf][soff] = bv_; } while (0)

  Chunk c0, c1, c2;
  LOADC(c0, 0);
  STORE_LDS(c0, 0);
  LOADC(c1, 32);          // in flight across the barrier + chunk-0 compute
  __syncthreads();

  int p = 0;
#pragma unroll 2
  for (int kc = 0; kc < 16; ++kc) {
    if (kc + 2 < 16) LOADC(c2, (kc + 2) * 32);   // issue 2 steps ahead
    short8 a0 = *(const short8*)&aT[p][aoff0];
    short8 a1 = *(const short8*)&aT[p][aoff0 + 16 * LDA];
    short8 b0 = *(const short8*)&bT[p][boff0];
    short8 b1 = *(const short8*)&bT[p][boff0 + 16 * LDA];
    acc00 = __builtin_amdgcn_mfma_f32_16x16x32_bf16(a0, b0, acc00, 0, 0, 0);
    acc01 = __builtin_amdgcn_mfma_f32_16x16x32_bf16(a0, b1, acc01, 0, 0, 0);
    acc10 = __builtin_amdgcn_mfma_f32_16x16x32_bf16(a1, b0, acc10, 0, 0, 0);
    acc11 = __builtin_amdgcn_mfma_f32_16x16x32_bf16(a1, b1, acc11, 0, 0, 0);
    if (kc < 15) {
      STORE_LDS(c1, p ^ 1);   // c1 arrived long ago; vmcnt wait ~free
      __syncthreads();
      p ^= 1;
      c1 = c2;
    }
  }
#undef LOADC
#undef STORE_LDS

  const float pw0 = ipw[0], pw1 = ipw[1], pw2 = ipw[2];
  const float pb0 = ipb[0], pb1 = ipb[1], pb2 = ipb[2];
  f32x4 accs[2][2] = {{acc00, acc01}, {acc10, acc11}};
#pragma unroll
  for (int cj = 0; cj < 2; ++cj) {
    const int o = col0 + wc * 32 + cj * 16 + lm;
    const int l = o / 3;
    const int c = o - 3 * l;
    const float pw = (c == 0) ? pw0 : ((c == 1) ? pw1 : pw2);
    const float pb = (c == 0) ? pb0 : ((c == 1) ? pb1 : pb2);
#pragma unroll
    for (int ri = 0; ri < 2; ++ri) {
#pragma unroll
      for (int r = 0; r < 4; ++r) {
        const int row = row0 + wr * 32 + ri * 16 + (lane >> 4) * 4 + r;
        const float v = fmaf(accs[ri][cj][r], pw, pb);
        if (c == 0) qp[(size_t)row * L_ + l] = v;
        else        kvp[(size_t)row * 2 * L_ + 2 * l + (c - 1)] = v;
      }
    }
  }
}

// ---------------- Kernel B: rank-1 attention via per-batch interpolation ---
// G_=16-pt grid, Catmull-Rom. 512 blocks x 2 batches each; both batches'
// global loads hoisted upfront (batch-1 latency hides under batch-0 compute).
// kv staged with per-segment padding (stride 34 float2): 4 segs/wave-read
// stay conflict-cheap. Barrier analysis: the 3 per-iter barriers also order
// LDS reuse across iterations (red/kvs/part2/fgrid) — no extra barrier.
__global__ __launch_bounds__(256) void attn_kernel(
    const float* __restrict__ qp, const float* __restrict__ kvp,
    const float* __restrict__ x, const float* __restrict__ ow,
    const float* __restrict__ ob, float* __restrict__ out)
{
  __shared__ float2 kvs[16 * 34];  // 16 segments x 32 pairs (+2 pad)
  __shared__ float2 part2[256];
  __shared__ float  fgrid[G_];
  __shared__ float  red[8];
  const int tid = threadIdx.x;
  const int bb  = blockIdx.x * 2;

  // upfront global loads for BOTH batches
  float  qv[2][2], xr[2][2];
  float2 kvr[2][2];
#pragma unroll
  for (int t = 0; t < 2; ++t) {
    const int b = bb + t;
    qv[t][0] = qp[(size_t)b * L_ + tid];
    qv[t][1] = qp[(size_t)b * L_ + 256 + tid];
    xr[t][0] = x[(size_t)b * L_ + tid];
    xr[t][1] = x[(size_t)b * L_ + 256 + tid];
    const float2* kvg = (const float2*)&kvp[(size_t)b * 2 * L_];
    kvr[t][0] = kvg[tid];
    kvr[t][1] = kvg[tid + 256];
  }
  const float w0 = ow[0], b0 = ob[0];
  const float L2E = 1.44269504f;

#pragma unroll 1
  for (int t = 0; t < 2; ++t) {
    const int b = bb + t;
    kvs[(tid >> 5) * 34 + (tid & 31)] = kvr[t][0];
    const int j1 = tid + 256;
    kvs[(j1 >> 5) * 34 + (j1 & 31)] = kvr[t][1];
    const float q0 = qv[t][0], q1 = qv[t][1];

    float qmn = fminf(q0, q1), qmx = fmaxf(q0, q1);
#pragma unroll
    for (int off = 32; off; off >>= 1) {
      qmn = fminf(qmn, __shfl_xor(qmn, off));
      qmx = fmaxf(qmx, __shfl_xor(qmx, off));
    }
    if ((tid & 63) == 0) { red[tid >> 6] = qmn; red[4 + (tid >> 6)] = qmx; }
    __syncthreads();
    qmn = fminf(fminf(red[0], red[1]), fminf(red[2], red[3]));
    qmx = fmaxf(fmaxf(red[4], red[5]), fmaxf(red[6], red[7]));

    const float range = qmx - qmn;
    const float hstep = range * (1.f / (G_ - 1));
    const int g   = tid & (G_ - 1);      // grid point 0..15
    const int seg = tid >> 4;            // j-segment 0..15 (32 terms each)
    const float gq = (qmn + hstep * (float)g) * L2E;
    float num = 0.f, den = 0.f;
    const float4* kv4 = (const float4*)&kvs[seg * 34];
#pragma unroll 4
    for (int j = 0; j < 16; ++j) {
      float4 pr = kv4[j];                // k,v,k,v
      float e0 = __builtin_amdgcn_exp2f(gq * pr.x);
      den += e0; num = fmaf(e0, pr.y, num);
      float e1 = __builtin_amdgcn_exp2f(gq * pr.z);
      den += e1; num = fmaf(e1, pr.w, num);
    }
    part2[tid] = make_float2(num, den);
    __syncthreads();
    if (tid < G_) {
      float nsum = 0.f, dsum = 0.f;
#pragma unroll
      for (int s = 0; s < 16; ++s) {
        float2 pp = part2[tid + 16 * s];
        nsum += pp.x; dsum += pp.y;
      }
      fgrid[tid] = nsum / dsum;
    }
    __syncthreads();

    const float inv_h = (range > 1e-20f) ? (float)(G_ - 1) / range : 0.f;
#pragma unroll
    for (int ii = 0; ii < 2; ++ii) {
      const float q = ii ? q1 : q0;
      float u = (q - qmn) * inv_h;
      u = fminf(fmaxf(u, 0.f), (float)(G_ - 1));
      int gi = (int)u;
      gi = min(gi, G_ - 2);
      const float tt = u - (float)gi;
      const float p0 = fgrid[max(gi - 1, 0)];
      const float p1 = fgrid[gi];
      const float p2 = fgrid[gi + 1];
      const float p3 = fgrid[min(gi + 2, G_ - 1)];
      // Catmull-Rom
      const float f = 0.5f * (2.f * p1 + tt * ((p2 - p0)
                    + tt * ((2.f * p0 - 5.f * p1 + 4.f * p2 - p3)
                    + tt * (3.f * (p1 - p2) + p3 - p0))));
      const int i = ii * 256 + tid;
      out[(size_t)b * L_ + i] = fmaf(f, w0, b0) + xr[t][ii];
    }
  }
}

extern "C" void kernel_launch(void* const* d_in, const int* in_sizes, int n_in,
                              void* d_out, int out_size, void* d_ws, size_t ws_size,
                              hipStream_t stream) {
  const float* x     = (const float*)d_in[0];
  const float* qkv_w = (const float*)d_in[1];
  const float* ipw   = (const float*)d_in[2];
  const float* ipb   = (const float*)d_in[3];
  const float* ow    = (const float*)d_in[4];
  const float* ob    = (const float*)d_in[5];
  float* out = (float*)d_out;

  char* ws = (char*)d_ws;
  float* qp  = (float*)(ws);            // 2.0 MB
  float* kvp = (float*)(ws + 2097152);  // 4.0 MB

  gemm_kernel<<<dim3(384), dim3(256), 0, stream>>>(x, qkv_w, ipw, ipb, qp, kvp);

  attn_kernel<<<dim3(512), dim3(256), 0, stream>>>(qp, kvp, x, ow, ob, out);
}

// Round 15
// 18.809 us; speedup vs baseline: 1.7986x; 1.7986x over previous
//
#include <hip/hip_runtime.h>

#define B_   1024
#define DIM_ 512
#define L_   512
#define NOUT 1536
#define G_   16    // interpolation grid points per batch
#define LDA  40    // LDS row stride in ushorts (80 B): 2-way-max bank aliasing

typedef __attribute__((ext_vector_type(8))) short short8;
typedef __attribute__((ext_vector_type(4))) float f32x4;

// packed fp32x2 -> bf16x2 (RNE), one VALU op
__device__ __forceinline__ unsigned int cvtpk(float lo, float hi) {
  unsigned int r;
  asm("v_cvt_pk_bf16_f32 %0, %1, %2" : "=v"(r) : "v"(lo), "v"(hi));
  return r;
}

struct Chunk { float4 al, ah, bl, bh; };

// ---------------- Kernel A: fused cvt + MFMA GEMM + in_proj ----------------
// Exact R11 winner: 64x64 tile, BK=32, 4 waves x 32x32 quadrant, 2-deep
// register prefetch, fp32->bf16 cvt during staging, XCD-aware swizzle
// (3 col-tiles/XCD -> x + w panel L2-resident).
__global__ __launch_bounds__(256) void gemm_kernel(
    const float* __restrict__ x, const float* __restrict__ w,
    const float* __restrict__ ipw, const float* __restrict__ ipb,
    float* __restrict__ qp, float* __restrict__ kvp)
{
  __shared__ unsigned short aT[2][64 * LDA];   // 10 KB
  __shared__ unsigned short bT[2][64 * LDA];   // 10 KB

  const int tid  = threadIdx.x;
  const int lane = tid & 63;
  const int wv   = tid >> 6;
  const int bid  = blockIdx.x;
  const int xcd  = bid & 7, slot = bid >> 3;   // HW: xcd = dispatch_id % 8
  const int cb   = xcd * 3 + (slot >> 4);      // 3 col-tiles per XCD
  const int rb   = slot & 15;
  const int row0 = rb * 64;
  const int col0 = cb * 64;

  const int sr = tid >> 2;
  const int sc = (tid & 3) * 8;
  const float* xg = &x[(size_t)(row0 + sr) * DIM_ + sc];
  const float* wg = &w[(size_t)(col0 + sr) * DIM_ + sc];
  const int soff = sr * LDA + sc;

  const int wr = wv >> 1, wc = wv & 1;
  const int lm = lane & 15;
  const int kq = (lane >> 4) * 8;
  const int aoff0 = (wr * 32 + lm) * LDA + kq;
  const int boff0 = (wc * 32 + lm) * LDA + kq;

  f32x4 acc00 = {0,0,0,0}, acc01 = {0,0,0,0}, acc10 = {0,0,0,0}, acc11 = {0,0,0,0};

#define LOADC(dst, k0) do { \
    (dst).al = *(const float4*)(xg + (k0));     \
    (dst).ah = *(const float4*)(xg + (k0) + 4); \
    (dst).bl = *(const float4*)(wg + (k0));     \
    (dst).bh = *(const float4*)(wg + (k0) + 4); } while (0)
#define STORE_LDS(src, buf) do { \
    uint4 av_ = { cvtpk((src).al.x,(src).al.y), cvtpk((src).al.z,(src).al.w), \
                  cvtpk((src).ah.x,(src).ah.y), cvtpk((src).ah.z,(src).ah.w) }; \
    uint4 bv_ = { cvtpk((src).bl.x,(src).bl.y), cvtpk((src).bl.z,(src).bl.w), \
                  cvtpk((src).bh.x,(src).bh.y), cvtpk((src).bh.z,(src).bh.w) }; \
    *(uint4*)&aT[buf][soff] = av_; \
    *(uint4*)&bT[buf][soff] = bv_; } while (0)

  Chunk c0, c1, c2;
  LOADC(c0, 0);
  STORE_LDS(c0, 0);
  LOADC(c1, 32);          // in flight across the barrier + chunk-0 compute
  __syncthreads();

  int p = 0;
#pragma unroll 2
  for (int kc = 0; kc < 16; ++kc) {
    if (kc + 2 < 16) LOADC(c2, (kc + 2) * 32);   // issue 2 steps ahead
    short8 a0 = *(const short8*)&aT[p][aoff0];
    short8 a1 = *(const short8*)&aT[p][aoff0 + 16 * LDA];
    short8 b0 = *(const short8*)&bT[p][boff0];
    short8 b1 = *(const short8*)&bT[p][boff0 + 16 * LDA];
    acc00 = __builtin_amdgcn_mfma_f32_16x16x32_bf16(a0, b0, acc00, 0, 0, 0);
    acc01 = __builtin_amdgcn_mfma_f32_16x16x32_bf16(a0, b1, acc01, 0, 0, 0);
    acc10 = __builtin_amdgcn_mfma_f32_16x16x32_bf16(a1, b0, acc10, 0, 0, 0);
    acc11 = __builtin_amdgcn_mfma_f32_16x16x32_bf16(a1, b1, acc11, 0, 0, 0);
    if (kc < 15) {
      STORE_LDS(c1, p ^ 1);   // c1 arrived long ago; vmcnt wait ~free
      __syncthreads();
      p ^= 1;
      c1 = c2;
    }
  }
#undef LOADC
#undef STORE_LDS

  const float pw0 = ipw[0], pw1 = ipw[1], pw2 = ipw[2];
  const float pb0 = ipb[0], pb1 = ipb[1], pb2 = ipb[2];
  f32x4 accs[2][2] = {{acc00, acc01}, {acc10, acc11}};
#pragma unroll
  for (int cj = 0; cj < 2; ++cj) {
    const int o = col0 + wc * 32 + cj * 16 + lm;
    const int l = o / 3;
    const int c = o - 3 * l;
    const float pw = (c == 0) ? pw0 : ((c == 1) ? pw1 : pw2);
    const float pb = (c == 0) ? pb0 : ((c == 1) ? pb1 : pb2);
#pragma unroll
    for (int ri = 0; ri < 2; ++ri) {
#pragma unroll
      for (int r = 0; r < 4; ++r) {
        const int row = row0 + wr * 32 + ri * 16 + (lane >> 4) * 4 + r;
        const float v = fmaf(accs[ri][cj][r], pw, pb);
        if (c == 0) qp[(size_t)row * L_ + l] = v;
        else        kvp[(size_t)row * 2 * L_ + 2 * l + (c - 1)] = v;
      }
    }
  }
}

// ---------------- Kernel B: rank-1 attention via per-batch interpolation ---
// R11 structure (one block per batch, 1024 blocks) with G_=16. kv staged with
// per-segment padding (stride 34 float2 -> per-wave groups hit 4 distinct
// bank-quads, conflict-free broadcast). No runtime-indexed thread arrays
// (R14 lesson: they silently go to scratch).
__global__ __launch_bounds__(256) void attn_kernel(
    const float* __restrict__ qp, const float* __restrict__ kvp,
    const float* __restrict__ x, const float* __restrict__ ow,
    const float* __restrict__ ob, float* __restrict__ out)
{
  __shared__ float2 kvs[16 * 34];  // 16 segments x 32 pairs (+2 pad)
  __shared__ float2 part2[256];
  __shared__ float  fgrid[G_];
  __shared__ float  red[8];
  const int b = blockIdx.x, tid = threadIdx.x;
  const float2* __restrict__ kvg = (const float2*)&kvp[(size_t)b * 2 * L_];

  float q0 = qp[(size_t)b * L_ + tid];
  float q1 = qp[(size_t)b * L_ + 256 + tid];
  // hoisted residual loads (barriers pin global loads late otherwise)
  const float xres0 = x[(size_t)b * L_ + tid];
  const float xres1 = x[(size_t)b * L_ + 256 + tid];
  const float w0 = ow[0], b0 = ob[0];
  float2 t0 = kvg[tid], t1 = kvg[tid + 256];
  kvs[(tid >> 5) * 34 + (tid & 31)] = t0;
  const int j1 = tid + 256;
  kvs[(j1 >> 5) * 34 + (j1 & 31)] = t1;

  float qmn = fminf(q0, q1), qmx = fmaxf(q0, q1);
#pragma unroll
  for (int off = 32; off; off >>= 1) {
    qmn = fminf(qmn, __shfl_xor(qmn, off));
    qmx = fmaxf(qmx, __shfl_xor(qmx, off));
  }
  if ((tid & 63) == 0) { red[tid >> 6] = qmn; red[4 + (tid >> 6)] = qmx; }
  __syncthreads();
  qmn = fminf(fminf(red[0], red[1]), fminf(red[2], red[3]));
  qmx = fmaxf(fmaxf(red[4], red[5]), fmaxf(red[6], red[7]));

  const float L2E = 1.44269504f;
  const float range = qmx - qmn;
  const float hstep = range * (1.f / (G_ - 1));
  const int g   = tid & (G_ - 1);      // grid point 0..15
  const int seg = tid >> 4;            // j-segment 0..15 (32 terms each)
  const float gq = (qmn + hstep * (float)g) * L2E;
  float num = 0.f, den = 0.f;
  const float4* kv4 = (const float4*)&kvs[seg * 34];
#pragma unroll 4
  for (int j = 0; j < 16; ++j) {
    float4 pr = kv4[j];                // k,v,k,v (broadcast within 16-lane group)
    float e0 = __builtin_amdgcn_exp2f(gq * pr.x);
    den += e0; num = fmaf(e0, pr.y, num);
    float e1 = __builtin_amdgcn_exp2f(gq * pr.z);
    den += e1; num = fmaf(e1, pr.w, num);
  }
  part2[tid] = make_float2(num, den);
  __syncthreads();
  if (tid < G_) {
    float nsum = 0.f, dsum = 0.f;
#pragma unroll
    for (int s = 0; s < 16; ++s) {
      float2 pp = part2[tid + 16 * s];
      nsum += pp.x; dsum += pp.y;
    }
    fgrid[tid] = nsum / dsum;
  }
  __syncthreads();

  const float inv_h = (range > 1e-20f) ? (float)(G_ - 1) / range : 0.f;
#pragma unroll
  for (int ii = 0; ii < 2; ++ii) {
    const float q = ii ? q1 : q0;
    float u = (q - qmn) * inv_h;
    u = fminf(fmaxf(u, 0.f), (float)(G_ - 1));
    int gi = (int)u;
    gi = min(gi, G_ - 2);
    const float t = u - (float)gi;
    const float p0 = fgrid[max(gi - 1, 0)];
    const float p1 = fgrid[gi];
    const float p2 = fgrid[gi + 1];
    const float p3 = fgrid[min(gi + 2, G_ - 1)];
    // Catmull-Rom
    const float f = 0.5f * (2.f * p1 + t * ((p2 - p0)
                  + t * ((2.f * p0 - 5.f * p1 + 4.f * p2 - p3)
                  + t * (3.f * (p1 - p2) + p3 - p0))));
    const int i = ii * 256 + tid;
    out[(size_t)b * L_ + i] = fmaf(f, w0, b0) + (ii ? xres1 : xres0);
  }
}

extern "C" void kernel_launch(void* const* d_in, const int* in_sizes, int n_in,
                              void* d_out, int out_size, void* d_ws, size_t ws_size,
                              hipStream_t stream) {
  const float* x     = (const float*)d_in[0];
  const float* qkv_w = (const float*)d_in[1];
  const float* ipw   = (const float*)d_in[2];
  const float* ipb   = (const float*)d_in[3];
  const float* ow    = (const float*)d_in[4];
  const float* ob    = (const float*)d_in[5];
  float* out = (float*)d_out;

  char* ws = (char*)d_ws;
  float* qp  = (float*)(ws);            // 2.0 MB
  float* kvp = (float*)(ws + 2097152);  // 4.0 MB

  gemm_kernel<<<dim3(384), dim3(256), 0, stream>>>(x, qkv_w, ipw, ipb, qp, kvp);

  attn_kernel<<<dim3(B_), dim3(256), 0, stream>>>(qp, kvp, x, ow, ob, out);
}